// Round 1
// baseline (1002.835 us; speedup 1.0000x reference)
//
#include <hip/hip_runtime.h>

// Problem constants
#define VV 1000
#define OO 64
#define LL 64
#define BB 128

// Branch metadata: fh = {5,10,15,20}, v-chunks = {2,4,6,8} (uniform ~640KB work/block)
// spart layout (floats): per branch region, [o][chunk][f][b], b innermost (coalesced)
// region bases (floats): br0=0 (64*2*5*128=81920), br1=81920 (327680),
//                        br2=409600 (737280), br3=1146880 (1310720); total 2457600 floats

// ---------------------------------------------------------------------------
// Kernel 1: build per-(v,l) 128-bit batch masks.  mask[(v*64+l)*2 + (b>>6)] |= bit(b&63)
__global__ void build_masks(const int* __restrict__ tokens,
                            unsigned long long* __restrict__ mask) {
    int i = blockIdx.x * 256 + threadIdx.x;   // 0..8191 == b*64 + l
    int b = i >> 6, l = i & 63;
    int v = tokens[i];
    atomicOr(&mask[(((long)v << 6) | l) * 2 + (b >> 6)], 1ull << (b & 63));
}

// ---------------------------------------------------------------------------
// Kernel 2: dense-stream W slabs, scatter hits into LDS accumulator, dump partials.
__global__ __launch_bounds__(512) void branch_accum(
    const float* __restrict__ W0, const float* __restrict__ W1,
    const float* __restrict__ W2, const float* __restrict__ W3,
    const unsigned long long* __restrict__ mask,
    float* __restrict__ spart)
{
    __shared__ float s[20 * 128];   // max fh=20 -> 10 KB

    int id = blockIdx.x;
    int o, ch, fh, nch, vc;
    const float* W;
    long base;
    if (id < 128)      { int t = id;       o = t >> 1; ch = t & 1; fh = 5;  nch = 2; vc = 500; W = W0; base = 0; }
    else if (id < 384) { int t = id - 128; o = t >> 2; ch = t & 3; fh = 10; nch = 4; vc = 250; W = W1; base = 81920; }
    else if (id < 768) { int t = id - 384; o = t / 6;  ch = t % 6; fh = 15; nch = 6; vc = 167; W = W2; base = 409600; }
    else               { int t = id - 768; o = t >> 3; ch = t & 7; fh = 20; nch = 8; vc = 125; W = W3; base = 1146880; }

    int v0 = ch * vc;
    int v1 = min(VV, v0 + vc);

    int tid  = threadIdx.x;
    int lane = tid & 63;
    int wv   = tid >> 6;          // 8 waves per block

    for (int i = tid; i < fh * 128; i += 512) s[i] = 0.f;
    __syncthreads();

    const float* slab = W + (long)o * VV * fh * LL;   // W[o, v, f, l]

    for (int v = v0 + wv; v < v1; v += 8) {
        const unsigned long long* mp = mask + (((long)v << 6 | lane) << 1);
        unsigned long long m0 = mp[0];
        unsigned long long m1 = mp[1];
        if ((m0 | m1) != 0ull) {
            const float* row = slab + (long)v * (fh * LL) + lane;
            for (int f = 0; f < fh; ++f) {
                float w = row[f * LL];               // coalesced 256B row (active lanes only)
                unsigned long long m = m0;
                while (m) {
                    int b = __ffsll(m) - 1; m &= m - 1;
                    atomicAdd(&s[f * 128 + b], w);   // ds_add_f32
                }
                m = m1;
                while (m) {
                    int b = __ffsll(m) - 1; m &= m - 1;
                    atomicAdd(&s[f * 128 + 64 + b], w);
                }
            }
        }
    }
    __syncthreads();

    float* out = spart + base + ((long)(o * nch + ch) * fh) * 128;
    for (int i = tid; i < fh * 128; i += 512) out[i] = s[i];
}

// ---------------------------------------------------------------------------
// Kernel 3: reduce v-chunk partials, +bias, relu, max over f, m/sqrt(1+m^2).
// feats layout: [k][b] with k = br*64+o  (coalesced writes & final-kernel reads)
__global__ void reduce_act(const float* __restrict__ spart,
                           const float* __restrict__ b0, const float* __restrict__ b1,
                           const float* __restrict__ b2, const float* __restrict__ b3,
                           float* __restrict__ feats)
{
    int blk = blockIdx.x;        // 0..255 = br*64 + o
    int br = blk >> 6, o = blk & 63;
    int b = threadIdx.x;         // 0..127

    int fh, nch; long base; const float* bias;
    if (br == 0)      { fh = 5;  nch = 2; base = 0;       bias = b0; }
    else if (br == 1) { fh = 10; nch = 4; base = 81920;   bias = b1; }
    else if (br == 2) { fh = 15; nch = 6; base = 409600;  bias = b2; }
    else              { fh = 20; nch = 8; base = 1146880; bias = b3; }

    float bo = bias[o];
    const float* p = spart + base + (long)(o * nch) * fh * 128;

    float mmax = 0.f;            // relu folds into max with 0
    for (int f = 0; f < fh; ++f) {
        float tot = 0.f;
        for (int ch = 0; ch < nch; ++ch) tot += p[(ch * fh + f) * 128 + b];
        mmax = fmaxf(mmax, tot + bo);
    }
    float r = mmax * rsqrtf(1.f + mmax * mmax);
    feats[blk * 128 + b] = r;
}

// ---------------------------------------------------------------------------
// Kernel 4: out[b][j] = blin[j] + sum_k feats[k][b] * Wlin[j][k]
__global__ void final_linear(const float* __restrict__ feats,
                             const float* __restrict__ Wlin,
                             const float* __restrict__ blin,
                             float* __restrict__ out)
{
    int t = threadIdx.x;         // 256 threads: b = t>>1, j = t&1
    int b = t >> 1, j = t & 1;
    float acc = blin[j];
    for (int k = 0; k < 256; ++k)
        acc += feats[k * 128 + b] * Wlin[j * 256 + k];
    out[b * 2 + j] = acc;
}

// ---------------------------------------------------------------------------
extern "C" void kernel_launch(void* const* d_in, const int* in_sizes, int n_in,
                              void* d_out, int out_size, void* d_ws, size_t ws_size,
                              hipStream_t stream) {
    const int*   tokens = (const int*)  d_in[0];
    const float* W1     = (const float*)d_in[1];
    const float* b1     = (const float*)d_in[2];
    const float* W2     = (const float*)d_in[3];
    const float* b2     = (const float*)d_in[4];
    const float* W3     = (const float*)d_in[5];
    const float* b3     = (const float*)d_in[6];
    const float* W4     = (const float*)d_in[7];
    const float* b4     = (const float*)d_in[8];
    const float* Wlin   = (const float*)d_in[9];
    const float* blin   = (const float*)d_in[10];
    float* out = (float*)d_out;

    char* ws = (char*)d_ws;
    unsigned long long* mask = (unsigned long long*)ws;        // 64000*16 = 1,024,000 B
    float* spart = (float*)(ws + 1048576);                     // 2,457,600 floats = 9,830,400 B
    float* feats = (float*)(ws + 1048576 + 9830400);           // 32768 floats = 131,072 B
    // total ws use: ~10.5 MiB

    hipMemsetAsync(mask, 0, 64000 * sizeof(unsigned long long) * 2, stream);
    build_masks<<<32, 256, 0, stream>>>(tokens, mask);
    branch_accum<<<1280, 512, 0, stream>>>(W1, W2, W3, W4, mask, spart);
    reduce_act<<<256, 128, 0, stream>>>(spart, b1, b2, b3, b4, feats);
    final_linear<<<1, 256, 0, stream>>>(feats, Wlin, blin, out);
}

// Round 2
// 718.915 us; speedup vs baseline: 1.3949x; 1.3949x over previous
//
#include <hip/hip_runtime.h>

#define VV 1000
#define OO 64
#define LL 64
#define BB 128

// spart layout (floats): per branch region, [o][chunk][f][b], b innermost
// region bases (floats): br0=0, br1=81920, br2=409600, br3=1146880; total 2457600

// ---------------------------------------------------------------------------
// Kernel 1: per-(v,l) 128-bit batch masks. mask[v*64+l] = {bits b0..63, bits b64..127}
__global__ void build_masks(const int* __restrict__ tokens,
                            unsigned long long* __restrict__ mask) {
    int i = blockIdx.x * 256 + threadIdx.x;   // 0..8191 == b*64 + l
    int b = i >> 6, l = i & 63;
    int v = tokens[i];
    atomicOr(&mask[(((long)v << 6) | l) * 2 + (b >> 6)], 1ull << (b & 63));
}

// ---------------------------------------------------------------------------
// Templated per-branch worker: U v-values in flight per wave iteration.
template<int FH, int U, int NCH>
__device__ __forceinline__ void run_branch(
    const float* __restrict__ W,
    const ulonglong2* __restrict__ mask,
    float* __restrict__ spart, long base,
    int o, int ch, int vc, float* s)
{
    int tid  = threadIdx.x;
    int lane = tid & 63;
    int wv   = tid >> 6;          // 8 waves/block

    int v0 = ch * vc;
    int v1 = min(VV, v0 + vc);

    for (int i = tid; i < FH * 128; i += 512) s[i] = 0.f;
    __syncthreads();

    const float* slab = W + (long)o * (VV * FH * LL);   // W[o, v, f, l]

    // wave wv owns v = v0+wv, v0+wv+8, ... ; grouped U at a time
    for (int vg = v0 + wv; vg < v1; vg += 8 * U) {
        ulonglong2 m[U];
        bool act[U];
        int vu[U];
        #pragma unroll
        for (int u = 0; u < U; ++u) {
            vu[u] = vg + 8 * u;
            if (vu[u] < v1) {
                m[u] = mask[(vu[u] << 6) | lane];
            } else {
                m[u].x = 0; m[u].y = 0;
            }
            act[u] = (m[u].x | m[u].y) != 0ull;
        }

        float w[U][FH];
        #pragma unroll
        for (int u = 0; u < U; ++u) {
            if (act[u]) {
                const float* row = slab + (long)vu[u] * (FH * LL) + lane;
                #pragma unroll
                for (int f = 0; f < FH; ++f)
                    w[u][f] = __builtin_nontemporal_load(row + f * LL);
            }
        }

        #pragma unroll
        for (int u = 0; u < U; ++u) {
            if (act[u]) {
                unsigned long long mm = m[u].x;
                while (mm) {
                    int b = __ffsll(mm) - 1; mm &= mm - 1;
                    float* sp = s + b;
                    #pragma unroll
                    for (int f = 0; f < FH; ++f) atomicAdd(&sp[f * 128], w[u][f]);
                }
                mm = m[u].y;
                while (mm) {
                    int b = __ffsll(mm) - 1; mm &= mm - 1;
                    float* sp = s + 64 + b;
                    #pragma unroll
                    for (int f = 0; f < FH; ++f) atomicAdd(&sp[f * 128], w[u][f]);
                }
            }
        }
    }
    __syncthreads();

    float* out = spart + base + ((long)(o * NCH + ch) * FH) * 128;
    for (int i = tid; i < FH * 128; i += 512) out[i] = s[i];
}

// ---------------------------------------------------------------------------
__global__ __launch_bounds__(512) void branch_accum(
    const float* __restrict__ W0, const float* __restrict__ W1,
    const float* __restrict__ W2, const float* __restrict__ W3,
    const ulonglong2* __restrict__ mask,
    float* __restrict__ spart)
{
    __shared__ float s[20 * 128];   // 10 KB (max FH)

    int id = blockIdx.x;
    if (id < 128) {
        int t = id;       run_branch<5, 6, 2>(W0, mask, spart, 0,       t >> 1, t & 1, 500, s);
    } else if (id < 384) {
        int t = id - 128; run_branch<10, 3, 4>(W1, mask, spart, 81920,  t >> 2, t & 3, 250, s);
    } else if (id < 768) {
        int t = id - 384; run_branch<15, 2, 6>(W2, mask, spart, 409600, t / 6,  t % 6, 167, s);
    } else {
        int t = id - 768; run_branch<20, 1, 8>(W3, mask, spart, 1146880, t >> 3, t & 7, 125, s);
    }
}

// ---------------------------------------------------------------------------
template<int FH, int NCH>
__device__ __forceinline__ void reduce_branch(
    const float* __restrict__ p, float bo, float* __restrict__ feats,
    int blk, int b)
{
    float mmax = 0.f;     // relu folds into max with 0
    #pragma unroll
    for (int f = 0; f < FH; ++f) {
        float tot = 0.f;
        #pragma unroll
        for (int ch = 0; ch < NCH; ++ch) tot += p[(ch * FH + f) * 128 + b];
        mmax = fmaxf(mmax, tot + bo);
    }
    feats[blk * 128 + b] = mmax * rsqrtf(1.f + mmax * mmax);
}

__global__ void reduce_act(const float* __restrict__ spart,
                           const float* __restrict__ b0, const float* __restrict__ b1,
                           const float* __restrict__ b2, const float* __restrict__ b3,
                           float* __restrict__ feats)
{
    int blk = blockIdx.x;        // 0..255 = br*64 + o
    int br = blk >> 6, o = blk & 63;
    int b = threadIdx.x;         // 0..127

    if (br == 0)
        reduce_branch<5, 2>(spart + (long)(o * 2) * 5 * 128,            b0[o], feats, blk, b);
    else if (br == 1)
        reduce_branch<10, 4>(spart + 81920 + (long)(o * 4) * 10 * 128,  b1[o], feats, blk, b);
    else if (br == 2)
        reduce_branch<15, 6>(spart + 409600 + (long)(o * 6) * 15 * 128, b2[o], feats, blk, b);
    else
        reduce_branch<20, 8>(spart + 1146880 + (long)(o * 8) * 20 * 128, b3[o], feats, blk, b);
}

// ---------------------------------------------------------------------------
__global__ void final_linear(const float* __restrict__ feats,
                             const float* __restrict__ Wlin,
                             const float* __restrict__ blin,
                             float* __restrict__ out)
{
    int t = threadIdx.x;         // 256 threads: b = t>>1, j = t&1
    int b = t >> 1, j = t & 1;
    float acc = blin[j];
    #pragma unroll 8
    for (int k = 0; k < 256; ++k)
        acc += feats[k * 128 + b] * Wlin[j * 256 + k];
    out[b * 2 + j] = acc;
}

// ---------------------------------------------------------------------------
extern "C" void kernel_launch(void* const* d_in, const int* in_sizes, int n_in,
                              void* d_out, int out_size, void* d_ws, size_t ws_size,
                              hipStream_t stream) {
    const int*   tokens = (const int*)  d_in[0];
    const float* W1     = (const float*)d_in[1];
    const float* b1     = (const float*)d_in[2];
    const float* W2     = (const float*)d_in[3];
    const float* b2     = (const float*)d_in[4];
    const float* W3     = (const float*)d_in[5];
    const float* b3     = (const float*)d_in[6];
    const float* W4     = (const float*)d_in[7];
    const float* b4     = (const float*)d_in[8];
    const float* Wlin   = (const float*)d_in[9];
    const float* blin   = (const float*)d_in[10];
    float* out = (float*)d_out;

    char* ws = (char*)d_ws;
    unsigned long long* mask = (unsigned long long*)ws;        // 1,024,000 B
    float* spart = (float*)(ws + 1048576);                     // 9,830,400 B
    float* feats = (float*)(ws + 1048576 + 9830400);           // 131,072 B

    hipMemsetAsync(mask, 0, 64000 * 2 * sizeof(unsigned long long), stream);
    build_masks<<<32, 256, 0, stream>>>(tokens, mask);
    branch_accum<<<1280, 512, 0, stream>>>(W1, W2, W3, W4,
                                           (const ulonglong2*)mask, spart);
    reduce_act<<<256, 128, 0, stream>>>(spart, b1, b2, b3, b4, feats);
    final_linear<<<1, 256, 0, stream>>>(feats, Wlin, blin, out);
}